// Round 3
// baseline (94.674 us; speedup 1.0000x reference)
//
#include <hip/hip_runtime.h>
#include <hip/hip_bf16.h>

// Problem constants
#define NB    4096          // batch
#define ND    256           // dim
#define NP    2             // positives per anchor
#define TOT   (NB * 3)      // 12288 rows: [a | p0 | p1]
#define TILES 8             // 8 x 16 = 128 cols per block
#define IMIN_SENT (-1073741824)      // mask sentinel; < any dot (|dot| <= 4.13M)
#define INV_SCALE (1.0f / 16129.0f)  // 1/(127*127)

// F2 is FRAGMENT-MAJOR i8 (R13 layout): for 16-row group g, K-block kk (64
// i8), the 1024-B block F2[g*4096 + kk*1024 + (quad*16 + r15)*16 + j] holds
// K-byte kk*64 + quad*16 + j of row g*16 + r15. Fragment loads = lane*16
// contiguous b128.
typedef float f32x4 __attribute__((ext_vector_type(4)));
typedef int   i32x4 __attribute__((ext_vector_type(4)));

// ws layout (bytes)
#define WS_F_OFF    0                             // uchar[3 MB] i8 fragment-major
#define WS_POS_OFF  (TOT * 256)                   // float[4096*2] pos distances
#define WS_NEG_OFF  (WS_POS_OFF + NB * NP * 4)    // int[3][4096] neg-dot maxima

// Kernel 1: normalize rows of [a | p0 | p1] -> i8 (x127), fragment-major;
// p-rows also emit the exact fp32 positive distance. One wave per row.
// Blocks 0..47 additionally initialize negmax to the sentinel (stream-ordered
// before gram, so no reliance on workspace poison).
__global__ void norm_pos_kernel(const float* __restrict__ anchor,
                                const float* __restrict__ positive,
                                unsigned char* __restrict__ F2,
                                float* __restrict__ posArr,
                                int* __restrict__ negmax) {
    if (blockIdx.x < 48) negmax[blockIdx.x * 256 + threadIdx.x] = IMIN_SENT;

    int wid = threadIdx.x >> 6, lane = threadIdx.x & 63;
    int row = blockIdx.x * 4 + wid;              // grid = 3072
    int group = row >> 4, r15 = row & 15;
    int kk = lane >> 4, quad = (lane >> 2) & 3, jj = (lane & 3) * 4;
    int* dst = (int*)(F2 + (size_t)group * 4096 + kk * 1024 + (quad * 16 + r15) * 16 + jj);

    if (row < NB) {
        const float* src = anchor + (size_t)row * ND;
        float4 x = *(const float4*)(src + lane * 4);
        float ss = x.x * x.x + x.y * x.y + x.z * x.z + x.w * x.w;
        #pragma unroll
        for (int m = 1; m < 64; m <<= 1) ss += __shfl_xor(ss, m, 64);
        float inv = 127.0f / fmaxf(sqrtf(ss), 1e-12f);
        int b0 = (int)rintf(x.x * inv) & 0xff;
        int b1 = (int)rintf(x.y * inv) & 0xff;
        int b2 = (int)rintf(x.z * inv) & 0xff;
        int b3 = (int)rintf(x.w * inv) & 0xff;
        *dst = b0 | (b1 << 8) | (b2 << 16) | (b3 << 24);
    } else {
        int q = row - NB;
        int v = q >> 12;                         // 0 or 1
        int j = q & (NB - 1);
        const float* sp = positive + (size_t)(j * NP + v) * ND;
        const float* sa = anchor + (size_t)j * ND;
        float4 xp = *(const float4*)(sp + lane * 4);
        float4 xa = *(const float4*)(sa + lane * 4);
        float sspv = xp.x * xp.x + xp.y * xp.y + xp.z * xp.z + xp.w * xp.w;
        float ssa  = xa.x * xa.x + xa.y * xa.y + xa.z * xa.z + xa.w * xa.w;
        float dot  = xa.x * xp.x + xa.y * xp.y + xa.z * xp.z + xa.w * xp.w;
        #pragma unroll
        for (int m = 1; m < 64; m <<= 1) {
            sspv += __shfl_xor(sspv, m, 64);
            ssa  += __shfl_xor(ssa, m, 64);
            dot  += __shfl_xor(dot, m, 64);
        }
        float invp = 127.0f / fmaxf(sqrtf(sspv), 1e-12f);
        int b0 = (int)rintf(xp.x * invp) & 0xff;
        int b1 = (int)rintf(xp.y * invp) & 0xff;
        int b2 = (int)rintf(xp.z * invp) & 0xff;
        int b3 = (int)rintf(xp.w * invp) & 0xff;
        *dst = b0 | (b1 << 8) | (b2 << 16) | (b3 << 24);
        if (lane == 0) {
            float inva = 1.0f / fmaxf(sqrtf(ssa), 1e-12f);
            float invpf = invp * (1.0f / 127.0f);
            float dn = dot * inva * invpf;
            float sq = 2.0f - 2.0f * dn;
            posArr[j * NP + v] = sqrtf(fmaxf(sq, 1e-12f));
        }
    }
}

// Kernel 2: fused masked-max Gram, INT8. ONE structural change vs the 86.5 us
// R13 baseline: 64 rows/wave x 128 cols/block (was 32 x 256), so each
// ds_read_b128 of B feeds 4 MFMAs instead of 2 and per-CU LDS-read cycles
// drop 6144->768 b128 (was the 30 us critical path; MFMA floor is 5.9 us).
// Everything else R13-verbatim: 512 thr / 8 waves, grid 768 (3 jobs/CU,
// balanced), one barrier, barrier-free K-loop, async LDS staging (neutral
// in R2), separate finalize. LDS 32 KB + 0.5 KB slab.
__global__ __launch_bounds__(512) void gram_max_kernel(
        const unsigned char* __restrict__ F2,
        const int* __restrict__ labels,
        int* __restrict__ negmax) {
    __shared__ unsigned char ldsB[TILES * 4096];  // 32 KB
    __shared__ int slab[128];                     // column labels
    int tid = threadIdx.x;
    int wid = tid >> 6, lane = tid & 63;
    int l15 = lane & 15, quad = lane >> 4;

    int id = blockIdx.x;                         // 0..767
    int rbi  = id & 7;                           // row-block index (512 rows)
    int cci  = id >> 3;                          // col-chunk 0..95
    int part = cci >> 5;                         // 0=aa, 1=p0, 2=p1
    int cip  = cci & 31;                         // col-chunk within part
    int col0 = cip * 128;                        // batch col base (0..3968)

    int rowBase = rbi * 512 + wid * 64;          // 64 rows per wave

    // ---- B staging: async direct-to-LDS, 32 KB, linear layout.
    {
        const unsigned char* src = F2 + ((size_t)part * 256 + (size_t)cip * 8) * 4096
                                      + (size_t)wid * 1024 + lane * 16;
        #pragma unroll
        for (int j = 0; j < 4; ++j)
            __builtin_amdgcn_global_load_lds((const unsigned int*)(src + j * 8192),
                                             (unsigned int*)(ldsB + wid * 1024 + j * 8192), 16, 0, 0);
    }

    // ---- A preload (b128): 4 groups of 16 rows per wave = 64 rows.
    i32x4 af[4][4];
    #pragma unroll
    for (int s = 0; s < 4; ++s) {
        const unsigned char* ab = F2 + (size_t)(rbi * 32 + wid * 4 + s) * 4096 + lane * 16;
        #pragma unroll
        for (int kk = 0; kk < 4; ++kk)
            af[s][kk] = *(const i32x4*)(ab + kk * 1024);
    }
    // Row labels, byte-packed (labels < 200 fit a byte). C row = quad*4+r.
    unsigned rlp[4];
    #pragma unroll
    for (int s = 0; s < 4; ++s) {
        const int* lb = labels + rowBase + s * 16 + quad * 4;
        rlp[s] = (unsigned)lb[0] | ((unsigned)lb[1] << 8)
               | ((unsigned)lb[2] << 16) | ((unsigned)lb[3] << 24);
    }
    if (tid < 128) slab[tid] = labels[col0 + tid];

    int vmax[4][4];
    #pragma unroll
    for (int s = 0; s < 4; ++s)
        #pragma unroll
        for (int r = 0; r < 4; ++r) vmax[s][r] = IMIN_SENT;

    __syncthreads();   // the ONLY barrier; drains vmcnt(0) incl. LDS-direct

    // ---- Barrier-free K-loop: 4 b128 ds_reads feed 16 MFMA per tile.
    #pragma unroll 2
    for (int ct = 0; ct < TILES; ++ct) {
        i32x4 bfr[4];
        #pragma unroll
        for (int kk = 0; kk < 4; ++kk)
            bfr[kk] = *(const i32x4*)&ldsB[ct * 4096 + kk * 1024 + lane * 16];

        int lc = slab[ct * 16 + l15];
        unsigned lcq = (unsigned)lc * 0x01010101u;

        i32x4 acc[4];
        #pragma unroll
        for (int s = 0; s < 4; ++s) acc[s] = (i32x4){0, 0, 0, 0};
        #pragma unroll
        for (int kk = 0; kk < 4; ++kk)
            #pragma unroll
            for (int s = 0; s < 4; ++s)
                acc[s] = __builtin_amdgcn_mfma_i32_16x16x64_i8(af[s][kk], bfr[kk], acc[s], 0, 0, 0);

        #pragma unroll
        for (int s = 0; s < 4; ++s) {
            unsigned x = rlp[s] ^ lcq;         // byte r == 0 iff labels equal
            #pragma unroll
            for (int r = 0; r < 4; ++r) {
                bool neq = ((x >> (8 * r)) & 0xffu) != 0u;
                int cand = neq ? acc[s][r] : IMIN_SENT;
                vmax[s][r] = vmax[s][r] > cand ? vmax[s][r] : cand;
            }
        }
    }

    // Reduce max across the 16 column-lanes (same quad = same rows)
    #pragma unroll
    for (int m = 1; m < 16; m <<= 1)
        #pragma unroll
        for (int s = 0; s < 4; ++s)
            #pragma unroll
            for (int r = 0; r < 4; ++r) {
                int o = __shfl_xor(vmax[s][r], m, 64);
                vmax[s][r] = vmax[s][r] > o ? vmax[s][r] : o;
            }

    if (l15 == 0) {
        #pragma unroll
        for (int s = 0; s < 4; ++s)
            #pragma unroll
            for (int r = 0; r < 4; ++r) {
                int row = rowBase + s * 16 + quad * 4 + r;
                atomicMax(&negmax[part * NB + row], vmax[s][r]);
            }
    }
}

// Kernel 3: negmax ints -> neg distances -> hinge -> mean. Reads only 48 KB.
__global__ void finalize_kernel(const int* __restrict__ negmax,
                                const float* __restrict__ posArr,
                                float* __restrict__ out) {
    int row = blockIdx.x * 256 + threadIdx.x;    // grid = 16 -> 4096 rows
    int ia = negmax[row];
    int i0 = negmax[NB + row];
    int i1 = negmax[2 * NB + row];
    int m0 = ia > i0 ? ia : i0;
    int m1 = ia > i1 ? ia : i1;
    // Sentinel path: if a row had all columns masked, value stays IMIN_SENT
    // -> huge neg distance -> hinge clamps to 0, matching the inf reference.
    float d0 = (float)m0 * INV_SCALE;
    float d1 = (float)m1 * INV_SCALE;
    float n0 = sqrtf(fmaxf(2.0f - 2.0f * d0, 1e-12f));
    float n1 = sqrtf(fmaxf(2.0f - 2.0f * d1, 1e-12f));
    float l = fmaxf(posArr[row * 2 + 0] - n0 + 1.0f, 0.0f)
            + fmaxf(posArr[row * 2 + 1] - n1 + 1.0f, 0.0f);
    int lane = threadIdx.x & 63, wid = threadIdx.x >> 6;
    #pragma unroll
    for (int m = 1; m < 64; m <<= 1) l += __shfl_xor(l, m, 64);
    __shared__ float wsum[4];
    if (lane == 0) wsum[wid] = l;
    __syncthreads();
    if (threadIdx.x == 0) {
        float s = wsum[0] + wsum[1] + wsum[2] + wsum[3];
        atomicAdd(out, s * (1.0f / (NB * NP)));
    }
}

extern "C" void kernel_launch(void* const* d_in, const int* in_sizes, int n_in,
                              void* d_out, int out_size, void* d_ws, size_t ws_size,
                              hipStream_t stream) {
    const float* anchor   = (const float*)d_in[0];
    const float* positive = (const float*)d_in[1];
    const int*   labels   = (const int*)d_in[2];
    float* out = (float*)d_out;

    unsigned char* F2 = (unsigned char*)((char*)d_ws + WS_F_OFF);
    float* posArr     = (float*)((char*)d_ws + WS_POS_OFF);
    int*   negmax     = (int*)((char*)d_ws + WS_NEG_OFF);

    hipMemsetAsync(d_out, 0, sizeof(float), stream);   // off the critical path
    norm_pos_kernel<<<TOT / 4, 256, 0, stream>>>(anchor, positive, F2, posArr, negmax);
    gram_max_kernel<<<(NB / 512) * 96, 512, 0, stream>>>(F2, labels, negmax);
    finalize_kernel<<<NB / 256, 256, 0, stream>>>(negmax, posArr, out);
}

// Round 4
// 86.817 us; speedup vs baseline: 1.0905x; 1.0905x over previous
//
#include <hip/hip_runtime.h>
#include <hip/hip_bf16.h>

// Problem constants
#define NB    4096          // batch
#define ND    256           // dim
#define NP    2             // positives per anchor
#define TOT   (NB * 3)      // 12288 rows: [a | p0 | p1]
#define TILES 8             // 8 x 16 = 128 cols per block
#define IMIN_SENT (-1073741824)      // mask sentinel; < any dot (|dot| <= 4.13M)
#define INV_SCALE (1.0f / 16129.0f)  // 1/(127*127)

// F2 is FRAGMENT-MAJOR i8 (R13 layout): for 16-row group g, K-block kk (64
// i8), the 1024-B block F2[g*4096 + kk*1024 + (quad*16 + r15)*16 + j] holds
// K-byte kk*64 + quad*16 + j of row g*16 + r15. Fragment loads = lane*16
// contiguous b128.
typedef float f32x4 __attribute__((ext_vector_type(4)));
typedef int   i32x4 __attribute__((ext_vector_type(4)));

// ws layout (bytes)
#define WS_F_OFF    0                             // uchar[3 MB] i8 fragment-major
#define WS_POS_OFF  (TOT * 256)                   // float[4096*2] pos distances
#define WS_NEG_OFF  (WS_POS_OFF + NB * NP * 4)    // int[3][4096] neg-dot maxima

// Kernel 1: normalize rows of [a | p0 | p1] -> i8 (x127), fragment-major;
// p-rows also emit the exact fp32 positive distance. One wave per row.
// Blocks 0..47 additionally initialize negmax to the sentinel (stream-ordered
// before gram, so no reliance on workspace poison).
__global__ void norm_pos_kernel(const float* __restrict__ anchor,
                                const float* __restrict__ positive,
                                unsigned char* __restrict__ F2,
                                float* __restrict__ posArr,
                                int* __restrict__ negmax) {
    if (blockIdx.x < 48) negmax[blockIdx.x * 256 + threadIdx.x] = IMIN_SENT;

    int wid = threadIdx.x >> 6, lane = threadIdx.x & 63;
    int row = blockIdx.x * 4 + wid;              // grid = 3072
    int group = row >> 4, r15 = row & 15;
    int kk = lane >> 4, quad = (lane >> 2) & 3, jj = (lane & 3) * 4;
    int* dst = (int*)(F2 + (size_t)group * 4096 + kk * 1024 + (quad * 16 + r15) * 16 + jj);

    if (row < NB) {
        const float* src = anchor + (size_t)row * ND;
        float4 x = *(const float4*)(src + lane * 4);
        float ss = x.x * x.x + x.y * x.y + x.z * x.z + x.w * x.w;
        #pragma unroll
        for (int m = 1; m < 64; m <<= 1) ss += __shfl_xor(ss, m, 64);
        float inv = 127.0f / fmaxf(sqrtf(ss), 1e-12f);
        int b0 = (int)rintf(x.x * inv) & 0xff;
        int b1 = (int)rintf(x.y * inv) & 0xff;
        int b2 = (int)rintf(x.z * inv) & 0xff;
        int b3 = (int)rintf(x.w * inv) & 0xff;
        *dst = b0 | (b1 << 8) | (b2 << 16) | (b3 << 24);
    } else {
        int q = row - NB;
        int v = q >> 12;                         // 0 or 1
        int j = q & (NB - 1);
        const float* sp = positive + (size_t)(j * NP + v) * ND;
        const float* sa = anchor + (size_t)j * ND;
        float4 xp = *(const float4*)(sp + lane * 4);
        float4 xa = *(const float4*)(sa + lane * 4);
        float sspv = xp.x * xp.x + xp.y * xp.y + xp.z * xp.z + xp.w * xp.w;
        float ssa  = xa.x * xa.x + xa.y * xa.y + xa.z * xa.z + xa.w * xa.w;
        float dot  = xa.x * xp.x + xa.y * xp.y + xa.z * xp.z + xa.w * xp.w;
        #pragma unroll
        for (int m = 1; m < 64; m <<= 1) {
            sspv += __shfl_xor(sspv, m, 64);
            ssa  += __shfl_xor(ssa, m, 64);
            dot  += __shfl_xor(dot, m, 64);
        }
        float invp = 127.0f / fmaxf(sqrtf(sspv), 1e-12f);
        int b0 = (int)rintf(xp.x * invp) & 0xff;
        int b1 = (int)rintf(xp.y * invp) & 0xff;
        int b2 = (int)rintf(xp.z * invp) & 0xff;
        int b3 = (int)rintf(xp.w * invp) & 0xff;
        *dst = b0 | (b1 << 8) | (b2 << 16) | (b3 << 24);
        if (lane == 0) {
            float inva = 1.0f / fmaxf(sqrtf(ssa), 1e-12f);
            float invpf = invp * (1.0f / 127.0f);
            float dn = dot * inva * invpf;
            float sq = 2.0f - 2.0f * dn;
            posArr[j * NP + v] = sqrtf(fmaxf(sq, 1e-12f));
        }
    }
}

// Kernel 2: fused masked-max Gram, INT8. Occupancy experiment (R4): the
// measured regime is stall-bound (R1: MfmaUtil 6% at 4.6 waves/CU -> 77 us;
// R0: 16 waves/CU -> ~32 us; floors are ~7 us). Per-wave state is cut to
// <=64 VGPR (af[4]=16, bfr[4]=16, acc=4, vmax=4) so 8 waves/SIMD fit ->
// 32 waves/CU, 2x the R0 residency. Geometry: 16 rows/wave, 128 rows x
// 128 cols per 512-thr block, 32 KB LDS (4 blocks/CU), grid 3072.
// __launch_bounds__(512, 8) enforces the 64-VGPR cap (check the counter!).
__global__ __launch_bounds__(512, 8) void gram_max_kernel(
        const unsigned char* __restrict__ F2,
        const int* __restrict__ labels,
        int* __restrict__ negmax) {
    __shared__ unsigned char ldsB[TILES * 4096];  // 32 KB
    __shared__ int slab[128];                     // column labels
    int tid = threadIdx.x;
    int wid = tid >> 6, lane = tid & 63;
    int l15 = lane & 15, quad = lane >> 4;

    int id = blockIdx.x;                         // 0..3071
    int rbi  = id & 31;                          // row-block (128 anchor rows)
    int cci  = id >> 5;                          // col-chunk 0..95
    int part = cci >> 5;                         // 0=aa, 1=p0, 2=p1
    int cip  = cci & 31;                         // col-chunk within part
    int col0 = cip * 128;                        // batch col base

    int rowBase = rbi * 128 + wid * 16;          // 16 rows per wave

    // ---- B staging: async direct-to-LDS, 32 KB, linear layout.
    {
        const unsigned char* src = F2 + ((size_t)part * 256 + (size_t)cip * 8) * 4096
                                      + (size_t)wid * 1024 + lane * 16;
        #pragma unroll
        for (int j = 0; j < 4; ++j)
            __builtin_amdgcn_global_load_lds((const unsigned int*)(src + j * 8192),
                                             (unsigned int*)(ldsB + wid * 1024 + j * 8192), 16, 0, 0);
    }

    // ---- A preload (b128): ONE 16-row group per wave = 16 regs.
    i32x4 af[4];
    {
        const unsigned char* ab = F2 + (size_t)(rbi * 8 + wid) * 4096 + lane * 16;
        #pragma unroll
        for (int kk = 0; kk < 4; ++kk)
            af[kk] = *(const i32x4*)(ab + kk * 1024);
    }
    // Row labels, byte-packed (labels < 200 fit a byte). C row = quad*4+r.
    unsigned rlp;
    {
        const int* lb = labels + rowBase + quad * 4;
        rlp = (unsigned)lb[0] | ((unsigned)lb[1] << 8)
            | ((unsigned)lb[2] << 16) | ((unsigned)lb[3] << 24);
    }
    if (tid < 128) slab[tid] = labels[col0 + tid];

    int vmax[4] = {IMIN_SENT, IMIN_SENT, IMIN_SENT, IMIN_SENT};

    __syncthreads();   // the ONLY barrier; drains vmcnt(0) incl. LDS-direct

    // ---- Barrier-free K-loop: 4 b128 ds_reads feed 4 MFMA per tile.
    #pragma unroll 2
    for (int ct = 0; ct < TILES; ++ct) {
        i32x4 bfr[4];
        #pragma unroll
        for (int kk = 0; kk < 4; ++kk)
            bfr[kk] = *(const i32x4*)&ldsB[ct * 4096 + kk * 1024 + lane * 16];

        int lc = slab[ct * 16 + l15];
        unsigned lcq = (unsigned)lc * 0x01010101u;

        i32x4 acc = (i32x4){0, 0, 0, 0};
        #pragma unroll
        for (int kk = 0; kk < 4; ++kk)
            acc = __builtin_amdgcn_mfma_i32_16x16x64_i8(af[kk], bfr[kk], acc, 0, 0, 0);

        unsigned x = rlp ^ lcq;                  // byte r == 0 iff labels equal
        #pragma unroll
        for (int r = 0; r < 4; ++r) {
            bool neq = ((x >> (8 * r)) & 0xffu) != 0u;
            int cand = neq ? acc[r] : IMIN_SENT;
            vmax[r] = vmax[r] > cand ? vmax[r] : cand;
        }
    }

    // Reduce max across the 16 column-lanes (same quad = same rows)
    #pragma unroll
    for (int m = 1; m < 16; m <<= 1)
        #pragma unroll
        for (int r = 0; r < 4; ++r) {
            int o = __shfl_xor(vmax[r], m, 64);
            vmax[r] = vmax[r] > o ? vmax[r] : o;
        }

    // Parallel epilogue: lanes l15=0..3 each push one r (static select --
    // no dynamic array index, which would spill to scratch).
    if (l15 < 4) {
        int v = vmax[0];
        v = (l15 == 1) ? vmax[1] : v;
        v = (l15 == 2) ? vmax[2] : v;
        v = (l15 == 3) ? vmax[3] : v;
        atomicMax(&negmax[part * NB + rowBase + quad * 4 + l15], v);
    }
}

// Kernel 3: negmax ints -> neg distances -> hinge -> mean. Reads only 48 KB.
__global__ void finalize_kernel(const int* __restrict__ negmax,
                                const float* __restrict__ posArr,
                                float* __restrict__ out) {
    int row = blockIdx.x * 256 + threadIdx.x;    // grid = 16 -> 4096 rows
    int ia = negmax[row];
    int i0 = negmax[NB + row];
    int i1 = negmax[2 * NB + row];
    int m0 = ia > i0 ? ia : i0;
    int m1 = ia > i1 ? ia : i1;
    // Sentinel path: if a row had all columns masked, value stays IMIN_SENT
    // -> huge neg distance -> hinge clamps to 0, matching the inf reference.
    float d0 = (float)m0 * INV_SCALE;
    float d1 = (float)m1 * INV_SCALE;
    float n0 = sqrtf(fmaxf(2.0f - 2.0f * d0, 1e-12f));
    float n1 = sqrtf(fmaxf(2.0f - 2.0f * d1, 1e-12f));
    float l = fmaxf(posArr[row * 2 + 0] - n0 + 1.0f, 0.0f)
            + fmaxf(posArr[row * 2 + 1] - n1 + 1.0f, 0.0f);
    int lane = threadIdx.x & 63, wid = threadIdx.x >> 6;
    #pragma unroll
    for (int m = 1; m < 64; m <<= 1) l += __shfl_xor(l, m, 64);
    __shared__ float wsum[4];
    if (lane == 0) wsum[wid] = l;
    __syncthreads();
    if (threadIdx.x == 0) {
        float s = wsum[0] + wsum[1] + wsum[2] + wsum[3];
        atomicAdd(out, s * (1.0f / (NB * NP)));
    }
}

extern "C" void kernel_launch(void* const* d_in, const int* in_sizes, int n_in,
                              void* d_out, int out_size, void* d_ws, size_t ws_size,
                              hipStream_t stream) {
    const float* anchor   = (const float*)d_in[0];
    const float* positive = (const float*)d_in[1];
    const int*   labels   = (const int*)d_in[2];
    float* out = (float*)d_out;

    unsigned char* F2 = (unsigned char*)((char*)d_ws + WS_F_OFF);
    float* posArr     = (float*)((char*)d_ws + WS_POS_OFF);
    int*   negmax     = (int*)((char*)d_ws + WS_NEG_OFF);

    hipMemsetAsync(d_out, 0, sizeof(float), stream);   // off the critical path
    norm_pos_kernel<<<TOT / 4, 256, 0, stream>>>(anchor, positive, F2, posArr, negmax);
    gram_max_kernel<<<(NB / 128) * 96, 512, 0, stream>>>(F2, labels, negmax);
    finalize_kernel<<<NB / 256, 256, 0, stream>>>(negmax, posArr, out);
}